// Round 13
// baseline (459.239 us; speedup 1.0000x reference)
//
#include <hip/hip_runtime.h>
#include <hip/hip_bf16.h>

typedef float f32x16 __attribute__((ext_vector_type(16)));
typedef int   i32x16 __attribute__((ext_vector_type(16)));
typedef int   i32x4  __attribute__((ext_vector_type(4)));
typedef __bf16 bf16x8 __attribute__((ext_vector_type(8)));

#define BM 256
#define BN 256
#define SLAB 16384   // bytes per slab (A or B): 256 rows x 64 B
// bf16: 64 B/row = 32 k (KS=32). i8: 64 B/row = 64 i8 (KS=64). Same byte layout.

__device__ __forceinline__ unsigned short f2bf(float f) {
    unsigned int u = __float_as_uint(f);
    u += 0x7fffu + ((u >> 16) & 1u);
    return (unsigned short)(u >> 16);
}

__device__ __forceinline__ void load_lds16(const void* g, void* l) {
    __builtin_amdgcn_global_load_lds((const __attribute__((address_space(1))) void*)g,
                                     (__attribute__((address_space(3))) void*)l,
                                     16, 0, 0);
}

// ---------------- conversion kernels ----------------
__global__ void cvt_f32_to_i8_k(const float* __restrict__ in,
                                signed char* __restrict__ out, int n) {
    int stride = gridDim.x * blockDim.x;
    for (int i = blockIdx.x * blockDim.x + threadIdx.x; i * 8 < n; i += stride) {
        float4 v0 = *reinterpret_cast<const float4*>(in + (size_t)i * 8);
        float4 v1 = *reinterpret_cast<const float4*>(in + (size_t)i * 8 + 4);
        union { signed char c[8]; int2 w; } u;
        float s = 127.0f / 6.0f;
        float f[8] = {v0.x, v0.y, v0.z, v0.w, v1.x, v1.y, v1.z, v1.w};
#pragma unroll
        for (int j = 0; j < 8; ++j) {
            int q = __float2int_rn(f[j] * s);
            q = q > 127 ? 127 : (q < -127 ? -127 : q);
            u.c[j] = (signed char)q;
        }
        *reinterpret_cast<int2*>(out + (size_t)i * 8) = u.w;
    }
}

__global__ void cvt_i32_to_i8_k(const int* __restrict__ in,
                                signed char* __restrict__ out, int n,
                                const int* __restrict__ zp) {
    int z = zp[0];
    int stride = gridDim.x * blockDim.x;
    for (int i = blockIdx.x * blockDim.x + threadIdx.x; i * 8 < n; i += stride) {
        int4 v0 = *reinterpret_cast<const int4*>(in + (size_t)i * 8);
        int4 v1 = *reinterpret_cast<const int4*>(in + (size_t)i * 8 + 4);
        union { signed char c[8]; int2 w; } u;
        int f[8] = {v0.x, v0.y, v0.z, v0.w, v1.x, v1.y, v1.z, v1.w};
#pragma unroll
        for (int j = 0; j < 8; ++j) {
            int q = f[j] - z;
            q = q > 127 ? 127 : (q < -128 ? -128 : q);
            u.c[j] = (signed char)q;
        }
        *reinterpret_cast<int2*>(out + (size_t)i * 8) = u.w;
    }
}

__global__ void cvt_i32_to_bf16_k(const int* __restrict__ in,
                                  unsigned short* __restrict__ out, int n,
                                  const int* __restrict__ zp) {
    int z = zp[0];
    int stride = gridDim.x * blockDim.x;
    for (int i = blockIdx.x * blockDim.x + threadIdx.x; i * 4 < n; i += stride) {
        int4 v = *reinterpret_cast<const int4*>(in + (size_t)i * 4);
        ushort4 o = make_ushort4(f2bf((float)(v.x - z)), f2bf((float)(v.y - z)),
                                 f2bf((float)(v.z - z)), f2bf((float)(v.w - z)));
        *reinterpret_cast<ushort4*>(out + (size_t)i * 4) = o;
    }
}

// ---------------- GEMM skeleton (R8 schedule + 32x32 MFMA) ------------------
// 256x256 tile, 8 waves (2 row x 4 col), wave tile 128x64 = 4x2 tiles of 32x32.
// Ring-4 slabs, 3 ahead, counted vmcnt(8), tail vmcnt(4)/vmcnt(0), ONE barrier
// per kstep, setprio around MFMA clusters (all verified R3-R8).
// Fragment mapping (32x32, K=16 bf16 / K=32 i8 per instr, 4 VGPR A/B):
//   row = lane&31, k-chunk kc = ks*2 + (lane>>5)  (16B chunks within 64B row)
// LDS pair-packed: rp=row>>1, inner=((row&1)<<6)|(kc<<4),
//   off = rp*128 + (((inner>>4) ^ rp) & 7)<<4   (same swizzle as R3-R12).
// C/D: col = lane&31, row = (reg&3) + 8*(reg>>2) + 4*(lane>>5)  [m74/m101].

#define KSTEP32(SS, VMSTR, DO_STAGE, FRAGT, MFMA)                              \
  {                                                                            \
    asm volatile("s_waitcnt " VMSTR ::: "memory");                             \
    __builtin_amdgcn_s_barrier();                                              \
    const int s_ = (SS);                                                       \
    const char* As = smem + (s_ & 3) * SLAB;                                   \
    const char* Bs = smem + 65536 + (s_ & 3) * SLAB;                           \
    FRAGT a[2][2], b[2][2];                                                    \
    _Pragma("unroll") for (int nt = 0; nt < 2; ++nt)                           \
      _Pragma("unroll") for (int ks = 0; ks < 2; ++ks) {                       \
        int g = wc * 64 + nt * 32 + l31;                                       \
        int rp = g >> 1;                                                       \
        int inner = ((g & 1) << 6) | ((ks * 2 + lhi) << 4);                    \
        int off = rp * 128 + ((((inner >> 4) ^ rp) & 7) << 4);                 \
        b[nt][ks] = *reinterpret_cast<const FRAGT*>(Bs + off);                 \
      }                                                                        \
    _Pragma("unroll") for (int mt = 0; mt < 2; ++mt)                           \
      _Pragma("unroll") for (int ks = 0; ks < 2; ++ks) {                       \
        int g = wr * 128 + mt * 32 + l31;                                      \
        int rp = g >> 1;                                                       \
        int inner = ((g & 1) << 6) | ((ks * 2 + lhi) << 4);                    \
        int off = rp * 128 + ((((inner >> 4) ^ rp) & 7) << 4);                 \
        a[mt][ks] = *reinterpret_cast<const FRAGT*>(As + off);                 \
      }                                                                        \
    if (DO_STAGE) stageA(s_ + 3);                                              \
    __builtin_amdgcn_s_setprio(1);                                             \
    _Pragma("unroll") for (int mt = 0; mt < 2; ++mt)                           \
      _Pragma("unroll") for (int nt = 0; nt < 2; ++nt)                         \
        _Pragma("unroll") for (int ks = 0; ks < 2; ++ks)                       \
          acc[mt][nt] = MFMA(a[mt][ks], b[nt][ks], acc[mt][nt]);               \
    __builtin_amdgcn_s_setprio(0);                                             \
    _Pragma("unroll") for (int mt = 0; mt < 2; ++mt)                           \
      _Pragma("unroll") for (int ks = 0; ks < 2; ++ks) {                       \
        int g = wr * 128 + (mt + 2) * 32 + l31;                                \
        int rp = g >> 1;                                                       \
        int inner = ((g & 1) << 6) | ((ks * 2 + lhi) << 4);                    \
        int off = rp * 128 + ((((inner >> 4) ^ rp) & 7) << 4);                 \
        a[mt][ks] = *reinterpret_cast<const FRAGT*>(As + off);                 \
      }                                                                        \
    if (DO_STAGE) stageB(s_ + 3);                                              \
    __builtin_amdgcn_s_setprio(1);                                             \
    _Pragma("unroll") for (int mt = 0; mt < 2; ++mt)                           \
      _Pragma("unroll") for (int nt = 0; nt < 2; ++nt)                         \
        _Pragma("unroll") for (int ks = 0; ks < 2; ++ks)                       \
          acc[mt + 2][nt] = MFMA(a[mt][ks], b[nt][ks], acc[mt + 2][nt]);       \
    __builtin_amdgcn_s_setprio(0);                                             \
  }

#define MFMA_BF16_32(aa, bb, cc) __builtin_amdgcn_mfma_f32_32x32x16_bf16(aa, bb, cc, 0, 0, 0)
#define MFMA_I8_32(aa, bb, cc)   __builtin_amdgcn_mfma_i32_32x32x32_i8(aa, bb, cc, 0, 0, 0)

// ---------------- GEMM1: h = gelu(dequant(xq * wfcq^T)+b) -------------------
__global__ __launch_bounds__(512, 2) void gemm_fc_i8(
    const signed char* __restrict__ A,   // xq [M,K] i8
    const signed char* __restrict__ Bt,  // wfcq [N,K] i8
    unsigned short* __restrict__ Cout,   // h bf16
    const int* __restrict__ bias_q,
    const float* __restrict__ s_w_p,
    const float* __restrict__ s_b_p,
    const int* __restrict__ z_b_p,
    int M, int N, int K)
{
    extern __shared__ char smem[];

    const int tid  = threadIdx.x;
    const int wave = tid >> 6;
    const int lane = tid & 63;
    const int wr = wave >> 2;        // 0..1 : 128-row half
    const int wc = wave & 3;         // 0..3 : 64-col quarter
    const int l31 = lane & 31;
    const int lhi = lane >> 5;

    const int bid  = blockIdx.x;
    const int x8   = bid & 7;
    const int j32  = (bid >> 3) & 31;
    const int rnd  = bid >> 8;
    const int brow = (4 * x8 + (j32 >> 3)) * BM;
    const int bcol = (rnd * 8 + (j32 & 7)) * BN;

    const int NSLAB = K / 64;            // 64 i8 per slab-row

    auto stageA = [&](int s) {
        char* base = smem + (s & 3) * SLAB;
#pragma unroll
        for (int h = 0; h < 2; ++h) {
            int p  = h * 512 + tid;
            int rp = p >> 3;
            int j  = (p & 7) ^ (rp & 7);
            const signed char* src =
                A + (size_t)(brow + 2 * rp + (j >> 2)) * K + s * 64 + (j & 3) * 16;
            void* dst = base + (h * 512 + wave * 64) * 16;
            load_lds16(src, dst);
        }
    };
    auto stageB = [&](int s) {
        char* base = smem + 65536 + (s & 3) * SLAB;
#pragma unroll
        for (int h = 0; h < 2; ++h) {
            int p  = h * 512 + tid;
            int rp = p >> 3;
            int j  = (p & 7) ^ (rp & 7);
            const signed char* src =
                Bt + (size_t)(bcol + 2 * rp + (j >> 2)) * K + s * 64 + (j & 3) * 16;
            void* dst = base + (h * 512 + wave * 64) * 16;
            load_lds16(src, dst);
        }
    };

    i32x16 acc[4][2] = {};

    stageA(0); stageB(0);
    stageA(1); stageB(1);
    stageA(2); stageB(2);

    for (int s = 0; s < NSLAB - 2; ++s) {
        KSTEP32(s, "vmcnt(8)", (s + 3 < NSLAB), i32x4, MFMA_I8_32);
    }
    KSTEP32(NSLAB - 2, "vmcnt(4)", false, i32x4, MFMA_I8_32);
    KSTEP32(NSLAB - 1, "vmcnt(0)", false, i32x4, MFMA_I8_32);

    // epilogue: dequant + bias + tanh-GELU -> bf16 via LDS, coalesced dwordx4
    const float s_w = s_w_p[0] * (6.0f / 127.0f);
    const float s_b = s_b_p[0];
    const int   z_b = z_b_p[0];

    __syncthreads();
    unsigned short* hl = (unsigned short*)smem;     // 256x256 bf16 = 128 KB
#pragma unroll
    for (int nt = 0; nt < 2; ++nt) {
        int col_local = wc * 64 + nt * 32 + l31;
        float bias = s_b * (float)(bias_q[bcol + col_local] - z_b);
        int c16 = col_local >> 3;
        int cb  = col_local & 7;
#pragma unroll
        for (int mt = 0; mt < 4; ++mt) {
#pragma unroll
            for (int reg = 0; reg < 16; ++reg) {
                int row_local = wr * 128 + mt * 32 + (reg & 3) + 8 * (reg >> 2) + 4 * lhi;
                float v = (float)acc[mt][nt][reg] * s_w + bias;
                float t2 = v * (1.5957691f + 0.0713548162f * v * v);
                float g  = v / (1.0f + __expf(-t2));
                int sw = c16 ^ (row_local & 31);
                hl[row_local * 256 + sw * 8 + cb] = f2bf(g);
            }
        }
    }
    __syncthreads();
#pragma unroll
    for (int it = 0; it < 16; ++it) {
        int lin = it * 512 + tid;      // 16B-chunk index, 0..8191
        int rl  = lin >> 5;
        int c16 = lin & 31;
        int sw  = c16 ^ (rl & 31);
        uint4 d = *reinterpret_cast<const uint4*>(hl + rl * 256 + sw * 8);
        *reinterpret_cast<uint4*>(Cout + (size_t)(brow + rl) * N + bcol + c16 * 8) = d;
    }
}

// ---------------- GEMM2: out = dequant(h * wproj^T)+b -----------------------
__global__ __launch_bounds__(512, 2) void gemm_proj(
    const unsigned short* __restrict__ A,
    const unsigned short* __restrict__ Bt,
    float* __restrict__ Cout,
    const int* __restrict__ bias_q,
    const float* __restrict__ s_w_p,
    const float* __restrict__ s_b_p,
    const int* __restrict__ z_b_p,
    int M, int N, int K)
{
    extern __shared__ char smem[];

    const int tid  = threadIdx.x;
    const int wave = tid >> 6;
    const int lane = tid & 63;
    const int wr = wave >> 2;
    const int wc = wave & 3;
    const int l31 = lane & 31;
    const int lhi = lane >> 5;

    const int bid  = blockIdx.x;
    const int x8   = bid & 7;
    const int j32  = (bid >> 3) & 31;
    const int rnd  = bid >> 8;
    const int brow = (4 * x8 + (j32 >> 3)) * BM;
    const int bcol = (rnd * 8 + (j32 & 7)) * BN;

    const int NSLAB = K / 32;            // 32 bf16 per slab-row

    auto stageA = [&](int s) {
        char* base = smem + (s & 3) * SLAB;
#pragma unroll
        for (int h = 0; h < 2; ++h) {
            int p  = h * 512 + tid;
            int rp = p >> 3;
            int j  = (p & 7) ^ (rp & 7);
            const unsigned short* src =
                A + (size_t)(brow + 2 * rp + (j >> 2)) * K + s * 32 + (j & 3) * 8;
            void* dst = base + (h * 512 + wave * 64) * 16;
            load_lds16(src, dst);
        }
    };
    auto stageB = [&](int s) {
        char* base = smem + 65536 + (s & 3) * SLAB;
#pragma unroll
        for (int h = 0; h < 2; ++h) {
            int p  = h * 512 + tid;
            int rp = p >> 3;
            int j  = (p & 7) ^ (rp & 7);
            const unsigned short* src =
                Bt + (size_t)(bcol + 2 * rp + (j >> 2)) * K + s * 32 + (j & 3) * 8;
            void* dst = base + (h * 512 + wave * 64) * 16;
            load_lds16(src, dst);
        }
    };

    f32x16 acc[4][2] = {};

    stageA(0); stageB(0);
    stageA(1); stageB(1);
    stageA(2); stageB(2);

    for (int s = 0; s < NSLAB - 2; ++s) {
        KSTEP32(s, "vmcnt(8)", (s + 3 < NSLAB), bf16x8, MFMA_BF16_32);
    }
    KSTEP32(NSLAB - 2, "vmcnt(4)", false, bf16x8, MFMA_BF16_32);
    KSTEP32(NSLAB - 1, "vmcnt(0)", false, bf16x8, MFMA_BF16_32);

    const float s_w = s_w_p[0];
    const float s_b = s_b_p[0];
    const int   z_b = z_b_p[0];
#pragma unroll
    for (int nt = 0; nt < 2; ++nt) {
        int col = bcol + wc * 64 + nt * 32 + l31;
        float bias = s_b * (float)(bias_q[col] - z_b);
#pragma unroll
        for (int mt = 0; mt < 4; ++mt) {
#pragma unroll
            for (int reg = 0; reg < 16; ++reg) {
                int row = brow + wr * 128 + mt * 32 + (reg & 3) + 8 * (reg >> 2) + 4 * lhi;
                Cout[(size_t)row * N + col] = acc[mt][nt][reg] * s_w + bias;
            }
        }
    }
}

extern "C" void kernel_launch(void* const* d_in, const int* in_sizes, int n_in,
                              void* d_out, int out_size, void* d_ws, size_t ws_size,
                              hipStream_t stream) {
    const float* x        = (const float*)d_in[0];
    const int*   w_fc_q   = (const int*)d_in[1];
    const int*   b_fc_q   = (const int*)d_in[2];
    const int*   w_proj_q = (const int*)d_in[3];
    const int*   b_proj_q = (const int*)d_in[4];
    const float* s_fc_w   = (const float*)d_in[5];
    const float* s_fc_b   = (const float*)d_in[6];
    const float* s_proj_w = (const float*)d_in[7];
    const float* s_proj_b = (const float*)d_in[8];
    const int*   z_fc_w   = (const int*)d_in[9];
    const int*   z_fc_b   = (const int*)d_in[10];
    const int*   z_proj_w = (const int*)d_in[11];
    const int*   z_proj_b = (const int*)d_in[12];

    const int M = 4 * 2048;
    const int E = 2048;
    const int H = 4 * 2048;

    // ws: xq i8 [M*E] | wfcq i8 [H*E] | wproj bf16 [E*H] | hb bf16 [M*H]
    size_t need = (size_t)M * E + (size_t)H * E
                + ((size_t)E * H + (size_t)M * H) * 2;
    if (ws_size < need) return;

    signed char*    xq    = (signed char*)d_ws;
    signed char*    wfcq  = xq + (size_t)M * E;
    unsigned short* wproj = (unsigned short*)(wfcq + (size_t)H * E);
    unsigned short* hb    = wproj + (size_t)E * H;

    hipFuncSetAttribute(reinterpret_cast<const void*>(gemm_fc_i8),
                        hipFuncAttributeMaxDynamicSharedMemorySize, 131072);
    hipFuncSetAttribute(reinterpret_cast<const void*>(gemm_proj),
                        hipFuncAttributeMaxDynamicSharedMemorySize, 131072);

    cvt_f32_to_i8_k<<<2048, 256, 0, stream>>>(x, xq, M * E);
    cvt_i32_to_i8_k<<<2048, 256, 0, stream>>>(w_fc_q, wfcq, H * E, z_fc_w);
    cvt_i32_to_bf16_k<<<2048, 256, 0, stream>>>(w_proj_q, wproj, E * H, z_proj_w);

    // GEMM1: i8 32x32x32 MFMA (exact int32 accum), fused dequant+bias+GELU
    gemm_fc_i8<<<dim3((M / BM) * (H / BN)), 512, 131072, stream>>>(
        xq, wfcq, hb, b_fc_q, s_fc_w, s_fc_b, z_fc_b, M, H, E);

    // GEMM2: bf16 32x32x16 MFMA ; scale+bias -> f32 out
    gemm_proj<<<dim3((M / BM) * (E / BN)), 512, 131072, stream>>>(
        hb, wproj, (float*)d_out, b_proj_q, s_proj_w, s_proj_b, z_proj_b, M, E, H);
}